// Round 1
// baseline (265.516 us; speedup 1.0000x reference)
//
#include <hip/hip_runtime.h>

#define N_NODES 16384
#define N_EDGES 524288
#define D 64

// ---- workspace layout ----
// [0, 32MiB)            : bitmask  (uint32[8388608])  -- zeroed each call
// [32MiB, +64KiB)       : deg      (int[16384])       -- zeroed each call
// [next, +64KiB)        : dinv     (float[16384])
// [next, +4MiB)         : xt       (float[16384*64])
// [next, +512KiB)       : flag     (uchar[524288])
#define BM_BYTES   33554432
#define DEG_OFF    33554432
#define DINV_OFF   33619968
#define XT_OFF     33685504
#define FLAG_OFF   37879808
#define ZERO_BYTES 33619968   // bitmask + deg

// xt = x @ theta  (16384x64 @ 64x64, fp32 vector ALU)
__global__ void gemm_xt(const float* __restrict__ x,
                        const float* __restrict__ theta,
                        float* __restrict__ xt) {
    __shared__ float th[64 * 64];
    int tid = threadIdx.x;
    for (int i = tid; i < 64 * 64; i += 256) th[i] = theta[i];
    __syncthreads();
    int row = blockIdx.x * 4 + (tid >> 6);
    int col = tid & 63;
    const float* xr = x + row * 64;
    float acc = 0.f;
#pragma unroll
    for (int k = 0; k < 64; ++k) acc += xr[k] * th[k * 64 + col];
    xt[row * 64 + col] = acc;
}

// exact dedupe via N^2 bitmask; count degree on COLUMN for first-setter,
// non-diagonal edges; emit per-edge effective flag
__global__ void dedupe_deg(const int* __restrict__ ei,
                           unsigned int* __restrict__ bm,
                           int* __restrict__ deg,
                           unsigned char* __restrict__ flag) {
    int e = blockIdx.x * 256 + threadIdx.x;
    if (e >= N_EDGES) return;
    int r = ei[e];
    int c = ei[N_EDGES + e];
    unsigned int bit = ((unsigned int)r << 14) | (unsigned int)c;
    unsigned int w = bit >> 5;
    unsigned int m = 1u << (bit & 31);
    unsigned int old = atomicOr(&bm[w], m);
    unsigned char f = 0;
    if (!(old & m) && (r != c)) {
        atomicAdd(&deg[c], 1);
        f = 1;
    }
    flag[e] = f;
}

// dinv = rsqrt(1 + deg)   (identity contributes the +1)
__global__ void make_dinv(const int* __restrict__ deg,
                          float* __restrict__ dinv) {
    int i = blockIdx.x * 256 + threadIdx.x;
    dinv[i] = rsqrtf((float)(deg[i] + 1));
}

// out[i][f] = d[i]*d[i]*xt[i][f]   (diagonal term; also initializes out)
__global__ void out_init(const float* __restrict__ xt,
                         const float* __restrict__ dinv,
                         float* __restrict__ out) {
    int t = blockIdx.x * 256 + threadIdx.x;
    int i = t >> 6;
    float d = dinv[i];
    out[t] = d * d * xt[t];
}

// out[r][f] += d[r]*d[c]*xt[c][f] for each effective edge; lane f = feature
__global__ void scatter(const int* __restrict__ ei,
                        const unsigned char* __restrict__ flag,
                        const float* __restrict__ dinv,
                        const float* __restrict__ xt,
                        float* __restrict__ out) {
    int t = blockIdx.x * 256 + threadIdx.x;   // 33,554,432 threads
    int e = t >> 6;
    int f = t & 63;
    if (!flag[e]) return;
    int r = ei[e];
    int c = ei[N_EDGES + e];
    float s = dinv[r] * dinv[c];
    atomicAdd(&out[r * 64 + f], s * xt[c * 64 + f]);
}

extern "C" void kernel_launch(void* const* d_in, const int* in_sizes, int n_in,
                              void* d_out, int out_size, void* d_ws, size_t ws_size,
                              hipStream_t stream) {
    const float* x     = (const float*)d_in[0];
    const int*   ei    = (const int*)d_in[1];
    const float* theta = (const float*)d_in[2];
    float* out = (float*)d_out;

    char* ws = (char*)d_ws;
    unsigned int*  bm   = (unsigned int*)ws;
    int*           deg  = (int*)(ws + DEG_OFF);
    float*         dinv = (float*)(ws + DINV_OFF);
    float*         xt   = (float*)(ws + XT_OFF);
    unsigned char* flag = (unsigned char*)(ws + FLAG_OFF);

    hipMemsetAsync(ws, 0, ZERO_BYTES, stream);

    gemm_xt<<<N_NODES / 4, 256, 0, stream>>>(x, theta, xt);
    dedupe_deg<<<N_EDGES / 256, 256, 0, stream>>>(ei, bm, deg, flag);
    make_dinv<<<N_NODES / 256, 256, 0, stream>>>(deg, dinv);
    out_init<<<N_NODES * D / 256, 256, 0, stream>>>(xt, dinv, out);
    scatter<<<N_EDGES * D / 256, 256, 0, stream>>>(ei, flag, dinv, xt, out);
}

// Round 3
// 194.350 us; speedup vs baseline: 1.3662x; 1.3662x over previous
//
#include <hip/hip_runtime.h>

#define N_NODES 16384
#define N_EDGES 524288
#define D 64

// ---- workspace layout (bytes) ----
// [0, 32MiB)    bitmask   uint32[2^23]   } zeroed
// +64KiB        deg       int[16384]     } zeroed
// +64KiB        rowcnt    int[16384]     } zeroed
// +64KiB        cursor    int[16384]     } zeroed
// +64KiB+64     rowptr    int[16385]
// +4MiB         xt        float[16384*64]
// +4MiB         xts       float[16384*64]
// +64KiB        dinv      float[16384]
// +512KiB       flag      uchar[524288]
// +2MiB         colidx    int[524288]
#define BM_BYTES    33554432u
#define DEG_OFF     (BM_BYTES)
#define ROWCNT_OFF  (DEG_OFF + 65536u)
#define CURSOR_OFF  (ROWCNT_OFF + 65536u)
#define ZERO_BYTES  (CURSOR_OFF + 65536u)          // bitmask + deg + rowcnt + cursor
#define ROWPTR_OFF  (ZERO_BYTES)
#define XT_OFF      (ROWPTR_OFF + 65600u)
#define XTS_OFF     (XT_OFF + 4194304u)
#define DINV_OFF    (XTS_OFF + 4194304u)
#define FLAG_OFF    (DINV_OFF + 65536u)
#define COLIDX_OFF  (FLAG_OFF + 524288u)

// xt = x @ theta  (16384x64 @ 64x64 fp32, vector ALU)
__global__ void gemm_xt(const float* __restrict__ x,
                        const float* __restrict__ theta,
                        float* __restrict__ xt) {
    __shared__ float th[64 * 64];
    int tid = threadIdx.x;
    for (int i = tid; i < 64 * 64; i += 256) th[i] = theta[i];
    __syncthreads();
    int row = blockIdx.x * 4 + (tid >> 6);
    int col = tid & 63;
    const float* xr = x + row * 64;
    float acc = 0.f;
#pragma unroll
    for (int k = 0; k < 64; ++k) acc += xr[k] * th[k * 64 + col];
    xt[row * 64 + col] = acc;
}

// exact dedupe via N^2 bitmask (first-setter wins); for effective
// (distinct, non-diagonal) edges: count column degree + row count, set flag
__global__ void dedupe_deg(const int* __restrict__ ei,
                           unsigned int* __restrict__ bm,
                           int* __restrict__ deg,
                           int* __restrict__ rowcnt,
                           unsigned char* __restrict__ flag) {
    int e = blockIdx.x * 256 + threadIdx.x;
    int r = ei[e];
    int c = ei[N_EDGES + e];
    unsigned int bit = ((unsigned int)r << 14) | (unsigned int)c;
    unsigned int old = atomicOr(&bm[bit >> 5], 1u << (bit & 31));
    unsigned char f = 0;
    if (!(old & (1u << (bit & 31))) && (r != c)) {
        atomicAdd(&deg[c], 1);
        atomicAdd(&rowcnt[r], 1);
        f = 1;
    }
    flag[e] = f;
}

// exclusive prefix scan of rowcnt[16384] -> rowptr[16385], single block
__global__ void scan_rowptr(const int* __restrict__ rowcnt,
                            int* __restrict__ rowptr) {
    __shared__ int sums[256];
    int t = threadIdx.x;
    int base = t * 64;
    int local[64];
    int s = 0;
#pragma unroll
    for (int i = 0; i < 64; ++i) { local[i] = rowcnt[base + i]; s += local[i]; }
    sums[t] = s;
    __syncthreads();
    // Hillis-Steele inclusive scan over 256 chunk sums
    for (int off = 1; off < 256; off <<= 1) {
        int v = (t >= off) ? sums[t - off] : 0;
        __syncthreads();
        sums[t] += v;
        __syncthreads();
    }
    int run = (t == 0) ? 0 : sums[t - 1];
#pragma unroll
    for (int i = 0; i < 64; ++i) { rowptr[base + i] = run; run += local[i]; }
    if (t == 255) rowptr[16384] = run;
}

// dinv = rsqrt(1+deg);  xts[i][f] = dinv[i]*xt[i][f]
__global__ void make_xts(const int* __restrict__ deg,
                         const float* __restrict__ xt,
                         float* __restrict__ xts,
                         float* __restrict__ dinv) {
    int t = blockIdx.x * 256 + threadIdx.x;
    int i = t >> 6;
    float d = rsqrtf((float)(deg[i] + 1));
    if ((t & 63) == 0) dinv[i] = d;
    xts[t] = d * xt[t];
}

// CSR column-index fill (atomics only on 16384 per-row cursors)
__global__ void fill_csr(const int* __restrict__ ei,
                         const unsigned char* __restrict__ flag,
                         const int* __restrict__ rowptr,
                         int* __restrict__ cursor,
                         int* __restrict__ colidx) {
    int e = blockIdx.x * 256 + threadIdx.x;
    if (!flag[e]) return;
    int r = ei[e];
    int c = ei[N_EDGES + e];
    int pos = rowptr[r] + atomicAdd(&cursor[r], 1);
    colidx[pos] = c;
}

// one wave per row, lane = feature:
// out[r][f] = dinv[r]*(xts[r][f] + sum_{c in row} xts[c][f])
// 4-wide unroll: 4 independent dependent-load chains per lane
__global__ void gather(const int* __restrict__ rowptr,
                       const int* __restrict__ colidx,
                       const float* __restrict__ dinv,
                       const float* __restrict__ xts,
                       float* __restrict__ out) {
    int r = blockIdx.x * 4 + (threadIdx.x >> 6);
    int f = threadIdx.x & 63;
    int s = rowptr[r], e = rowptr[r + 1];
    float acc0 = xts[r * 64 + f];
    float acc1 = 0.f, acc2 = 0.f, acc3 = 0.f;
    int i = s;
    for (; i + 3 < e; i += 4) {
        int c0 = colidx[i];
        int c1 = colidx[i + 1];
        int c2 = colidx[i + 2];
        int c3 = colidx[i + 3];
        acc0 += xts[c0 * 64 + f];
        acc1 += xts[c1 * 64 + f];
        acc2 += xts[c2 * 64 + f];
        acc3 += xts[c3 * 64 + f];
    }
    for (; i < e; ++i) acc0 += xts[colidx[i] * 64 + f];
    out[r * 64 + f] = dinv[r] * ((acc0 + acc1) + (acc2 + acc3));
}

extern "C" void kernel_launch(void* const* d_in, const int* in_sizes, int n_in,
                              void* d_out, int out_size, void* d_ws, size_t ws_size,
                              hipStream_t stream) {
    const float* x     = (const float*)d_in[0];
    const int*   ei    = (const int*)d_in[1];
    const float* theta = (const float*)d_in[2];
    float* out = (float*)d_out;

    char* ws = (char*)d_ws;
    unsigned int*  bm     = (unsigned int*)ws;
    int*           deg    = (int*)(ws + DEG_OFF);
    int*           rowcnt = (int*)(ws + ROWCNT_OFF);
    int*           cursor = (int*)(ws + CURSOR_OFF);
    int*           rowptr = (int*)(ws + ROWPTR_OFF);
    float*         xt     = (float*)(ws + XT_OFF);
    float*         xts    = (float*)(ws + XTS_OFF);
    float*         dinv   = (float*)(ws + DINV_OFF);
    unsigned char* flag   = (unsigned char*)(ws + FLAG_OFF);
    int*           colidx = (int*)(ws + COLIDX_OFF);

    hipMemsetAsync(ws, 0, ZERO_BYTES, stream);

    gemm_xt<<<N_NODES / 4, 256, 0, stream>>>(x, theta, xt);
    dedupe_deg<<<N_EDGES / 256, 256, 0, stream>>>(ei, bm, deg, rowcnt, flag);
    scan_rowptr<<<1, 256, 0, stream>>>(rowcnt, rowptr);
    make_xts<<<N_NODES * D / 256, 256, 0, stream>>>(deg, xt, xts, dinv);
    fill_csr<<<N_EDGES / 256, 256, 0, stream>>>(ei, flag, rowptr, cursor, colidx);
    gather<<<N_NODES / 4, 256, 0, stream>>>(rowptr, colidx, dinv, xts, out);
}